// Round 1
// baseline (518.756 us; speedup 1.0000x reference)
//
#include <hip/hip_runtime.h>
#include <hip/hip_bf16.h>

// Problem constants (from reference setup_inputs)
constexpr int MP = 10242;   // coarse vertices (output rows)
constexpr int B  = 16;      // batch
constexpr int M  = 40962;   // fine vertices
constexpr int F  = 128;     // features
constexpr int SCAN_THREADS = 1024;
constexpr int SCAN_ITEMS = (MP + SCAN_THREADS - 1) / SCAN_THREADS; // 11

// ---------------------------------------------------------------------------
// Kernel 1: histogram of rows -> counts[MP]
__global__ void hist_kernel(const int* __restrict__ rows,
                            int* __restrict__ counts, int nnz) {
    int k = blockIdx.x * blockDim.x + threadIdx.x;
    if (k < nnz) atomicAdd(&counts[rows[k]], 1);
}

// ---------------------------------------------------------------------------
// Kernel 2: single-block exclusive scan over counts -> offsets[MP+1], cursor[MP]
__global__ __launch_bounds__(SCAN_THREADS)
void scan_kernel(const int* __restrict__ counts,
                 int* __restrict__ offsets,
                 int* __restrict__ cursor) {
    __shared__ int lds[SCAN_THREADS];
    int t = threadIdx.x;
    int local[SCAN_ITEMS];
    int run = 0;
    int base_idx = t * SCAN_ITEMS;
    for (int i = 0; i < SCAN_ITEMS; ++i) {
        int idx = base_idx + i;
        int c = (idx < MP) ? counts[idx] : 0;
        local[i] = run;   // exclusive within this thread's chunk
        run += c;
    }
    lds[t] = run;
    __syncthreads();
    // Hillis-Steele inclusive scan over the 1024 per-thread sums
    for (int off = 1; off < SCAN_THREADS; off <<= 1) {
        int v = (t >= off) ? lds[t - off] : 0;
        __syncthreads();
        lds[t] += v;
        __syncthreads();
    }
    int excl = lds[t] - run;  // exclusive prefix for this thread's chunk
    for (int i = 0; i < SCAN_ITEMS; ++i) {
        int idx = base_idx + i;
        if (idx < MP) {
            int o = excl + local[i];
            offsets[idx] = o;
            cursor[idx]  = o;
        }
    }
    if (t == SCAN_THREADS - 1) offsets[MP] = lds[SCAN_THREADS - 1];
}

// ---------------------------------------------------------------------------
// Kernel 3: scatter (col, val) pairs into CSR order using cursor
__global__ void scatter_kernel(const int* __restrict__ rows,
                               const int* __restrict__ cols,
                               const float* __restrict__ vals,
                               int* __restrict__ cursor,
                               int* __restrict__ scol,
                               float* __restrict__ sval, int nnz) {
    int k = blockIdx.x * blockDim.x + threadIdx.x;
    if (k < nnz) {
        int p = rows[k];
        int pos = atomicAdd(&cursor[p], 1);
        scol[pos] = cols[k];
        sval[pos] = vals[k];
    }
}

// ---------------------------------------------------------------------------
// Kernel 4: main pooled gather. One wave per (p, b) output row.
// 64 lanes x float2 = 128 floats = full feature row, fully coalesced.
__global__ __launch_bounds__(256)
void pool_kernel(const float* __restrict__ x,
                 const int* __restrict__ offsets,
                 const int* __restrict__ scol,
                 const float* __restrict__ sval,
                 float* __restrict__ out) {
    int w    = blockIdx.x * 4 + (threadIdx.x >> 6); // global wave id
    int lane = threadIdx.x & 63;
    int p = w >> 4;   // w / B
    int b = w & 15;   // w % B
    int s = offsets[p];
    int e = offsets[p + 1];
    const float2* xb = (const float2*)x + (size_t)b * (size_t)M * (F / 2);
    float2 acc; acc.x = 0.f; acc.y = 0.f;
    for (int i = s; i < e; ++i) {
        int col = scol[i];
        float v = sval[i];
        float2 xv = xb[(size_t)col * (F / 2) + lane];
        acc.x = fmaf(v, xv.x, acc.x);
        acc.y = fmaf(v, xv.y, acc.y);
    }
    ((float2*)out)[((size_t)b * MP + p) * (F / 2) + lane] = acc;
}

// ---------------------------------------------------------------------------
extern "C" void kernel_launch(void* const* d_in, const int* in_sizes, int n_in,
                              void* d_out, int out_size, void* d_ws, size_t ws_size,
                              hipStream_t stream) {
    const float* x    = (const float*)d_in[0];
    const int*   rows = (const int*)d_in[1];
    const int*   cols = (const int*)d_in[2];
    const float* vals = (const float*)d_in[3];
    float* out = (float*)d_out;
    const int nnz = in_sizes[1];

    // Workspace layout (all int/float, 4B aligned):
    // counts[MP] | offsets[MP+1] | cursor[MP] | scol[nnz] | sval[nnz]
    int* counts  = (int*)d_ws;
    int* offsets = counts + MP;
    int* cursor  = offsets + (MP + 1);
    int* scol    = cursor + MP;
    float* sval  = (float*)(scol + nnz);

    // counts must be zeroed every call (ws is poisoned to 0xAA)
    hipMemsetAsync(counts, 0, MP * sizeof(int), stream);

    int nb = (nnz + 255) / 256;
    hist_kernel<<<nb, 256, 0, stream>>>(rows, counts, nnz);
    scan_kernel<<<1, SCAN_THREADS, 0, stream>>>(counts, offsets, cursor);
    scatter_kernel<<<nb, 256, 0, stream>>>(rows, cols, vals, cursor, scol, sval, nnz);

    // MP * B waves, 4 waves (256 threads) per block; MP*B = 163872 divisible by 4
    int pool_blocks = (MP * B) / 4;
    pool_kernel<<<pool_blocks, 256, 0, stream>>>(x, offsets, scol, sval, out);
}